// Round 15
// baseline (141.477 us; speedup 1.0000x reference)
//
#include <hip/hip_runtime.h>
#include <hip/hip_bf16.h>
#include <hip/hip_cooperative_groups.h>

namespace cg = cooperative_groups;

#define T_SEQ 2048
#define BH    32
#define NPART 16         // t-partials per head for M = V*K^T
#define PSTEP 2          // 64-wide steps per partial (NPART*PSTEP*64 == T_SEQ)

typedef __bf16 bf16x8 __attribute__((ext_vector_type(8)));
typedef float f32x4 __attribute__((ext_vector_type(4)));
typedef float f32x16 __attribute__((ext_vector_type(16)));
typedef unsigned int u32x4 __attribute__((ext_vector_type(4)));
typedef unsigned short ushort8v __attribute__((ext_vector_type(8)));

__device__ __forceinline__ unsigned short f2bf(float x) {
    __hip_bfloat16 b = __float2bfloat16(x);
    return __builtin_bit_cast(unsigned short, b);
}
__device__ __forceinline__ float bf2f(unsigned short u) {
    unsigned v = (unsigned)u << 16;
    return __builtin_bit_cast(float, v);
}
__device__ __forceinline__ void split_hl(float v, unsigned short& hi, unsigned short& lo) {
    hi = f2bf(v);
    lo = f2bf(v - bf2f(hi));
}
__device__ __forceinline__ unsigned pk2(unsigned short a, unsigned short b) {
    return (unsigned)a | ((unsigned)b << 16);
}
__device__ __forceinline__ f32x16 mfma32(bf16x8 a, bf16x8 b, f32x16 c) {
    return __builtin_amdgcn_mfma_f32_32x32x16_bf16(a, b, c, 0, 0, 0);
}
__device__ __forceinline__ bf16x8 ldfrag(const unsigned char* p) {
    return __builtin_bit_cast(bf16x8, *reinterpret_cast<const u32x4*>(p));
}

// ================= single cooperative kernel: build -> reduce -> apply =================
__global__ __launch_bounds__(256, 2)
void qattn_fused(const float* __restrict__ qkv,
                 float* __restrict__ Mpart, float* __restrict__ kpart,
                 float* __restrict__ vpart,
                 unsigned short* __restrict__ MhiG, unsigned short* __restrict__ MloG,
                 float* __restrict__ kssG, float* __restrict__ vsumG,
                 float* __restrict__ out) {
    __shared__ __align__(16) unsigned char smem[33024];
    const int tid = threadIdx.x;
    const int bx  = blockIdx.x;
    cg::grid_group grid = cg::this_grid();

    // ---------------- phase 1: partial M = V*K^T (512 blocks: bh = bx>>4, part = bx&15) ----
    {
        const int bh = bx >> 4, part = bx & (NPART - 1);
        const int b = bh >> 3, h = bh & 7;
        const int tbase = part * (PSTEP * 64);
        const float* kg = qkv + ((size_t)b * 1536 + 512 + h * 64) * 2048;
        const float* vg = qkv + ((size_t)b * 1536 + 1024 + h * 64) * 2048;

        unsigned char* Vhi_b = smem;
        unsigned char* Vlo_b = smem + 8192;
        unsigned char* Khi_b = smem + 16384;
        unsigned char* Klo_b = smem + 24576;

        const int c = tid >> 2, j = tid & 3;
        const int lane = tid & 63, l31 = lane & 31, hi = lane >> 5;
        const int wave = tid >> 6, qc = wave >> 1, qk = wave & 1;
        const int r7 = l31 & 7;

        f32x4 kv[4], vv[4];
        #pragma unroll
        for (int i = 0; i < 4; ++i) {
            kv[i] = *(const f32x4*)(kg + (size_t)c * 2048 + tbase + j * 16 + i * 4);
            vv[i] = *(const f32x4*)(vg + (size_t)c * 2048 + tbase + j * 16 + i * 4);
        }

        float ksum = 0.f, vsum = 0.f;
        f32x16 acc = {};

        for (int st = 0; st < PSTEP; ++st) {
            __syncthreads();
            unsigned short kh[16], kl[16], vh[16], vl[16];
            #pragma unroll
            for (int i = 0; i < 4; ++i)
                #pragma unroll
                for (int e = 0; e < 4; ++e) {
                    float kx = kv[i][e], vx = vv[i][e];
                    ksum += kx; vsum += vx;
                    split_hl(kx, kh[i * 4 + e], kl[i * 4 + e]);
                    split_hl(vx, vh[i * 4 + e], vl[i * 4 + e]);
                }
            const int s0a = c * 128 + 16 * ((2 * j) ^ (c & 7));
            const int s0b = c * 128 + 16 * ((2 * j + 1) ^ (c & 7));
            u32x4 w;
            w[0]=pk2(kh[0],kh[1]); w[1]=pk2(kh[2],kh[3]); w[2]=pk2(kh[4],kh[5]); w[3]=pk2(kh[6],kh[7]);
            *(u32x4*)(Khi_b + s0a) = w;
            w[0]=pk2(kh[8],kh[9]); w[1]=pk2(kh[10],kh[11]); w[2]=pk2(kh[12],kh[13]); w[3]=pk2(kh[14],kh[15]);
            *(u32x4*)(Khi_b + s0b) = w;
            w[0]=pk2(kl[0],kl[1]); w[1]=pk2(kl[2],kl[3]); w[2]=pk2(kl[4],kl[5]); w[3]=pk2(kl[6],kl[7]);
            *(u32x4*)(Klo_b + s0a) = w;
            w[0]=pk2(kl[8],kl[9]); w[1]=pk2(kl[10],kl[11]); w[2]=pk2(kl[12],kl[13]); w[3]=pk2(kl[14],kl[15]);
            *(u32x4*)(Klo_b + s0b) = w;
            w[0]=pk2(vh[0],vh[1]); w[1]=pk2(vh[2],vh[3]); w[2]=pk2(vh[4],vh[5]); w[3]=pk2(vh[6],vh[7]);
            *(u32x4*)(Vhi_b + s0a) = w;
            w[0]=pk2(vh[8],vh[9]); w[1]=pk2(vh[10],vh[11]); w[2]=pk2(vh[12],vh[13]); w[3]=pk2(vh[14],vh[15]);
            *(u32x4*)(Vhi_b + s0b) = w;
            w[0]=pk2(vl[0],vl[1]); w[1]=pk2(vl[2],vl[3]); w[2]=pk2(vl[4],vl[5]); w[3]=pk2(vl[6],vl[7]);
            *(u32x4*)(Vlo_b + s0a) = w;
            w[0]=pk2(vl[8],vl[9]); w[1]=pk2(vl[10],vl[11]); w[2]=pk2(vl[12],vl[13]); w[3]=pk2(vl[14],vl[15]);
            *(u32x4*)(Vlo_b + s0b) = w;

            if (st + 1 < PSTEP) {
                const int s0n = tbase + (st + 1) * 64;
                #pragma unroll
                for (int i = 0; i < 4; ++i) {
                    kv[i] = *(const f32x4*)(kg + (size_t)c * 2048 + s0n + j * 16 + i * 4);
                    vv[i] = *(const f32x4*)(vg + (size_t)c * 2048 + s0n + j * 16 + i * 4);
                }
            }
            __syncthreads();

            const int rowA = (qc * 32 + l31) * 128;
            const int rowB = (qk * 32 + l31) * 128;
            #pragma unroll
            for (int ks = 0; ks < 4; ++ks) {
                const int sl = 16 * ((2 * ks + hi) ^ r7);
                bf16x8 aH = ldfrag(Vhi_b + rowA + sl);
                bf16x8 aL = ldfrag(Vlo_b + rowA + sl);
                bf16x8 bH = ldfrag(Khi_b + rowB + sl);
                bf16x8 bL = ldfrag(Klo_b + rowB + sl);
                acc = mfma32(aH, bH, acc);
                acc = mfma32(aH, bL, acc);
                acc = mfma32(aL, bH, acc);
            }
        }

        {
            float t1 = ksum + __shfl_xor(ksum, 1);
            float t2 = t1 + __shfl_xor(t1, 2);
            float u1 = vsum + __shfl_xor(vsum, 1);
            float u2 = u1 + __shfl_xor(u1, 2);
            if (j == 0) {
                kpart[(size_t)bx * 64 + c] = t2;
                vpart[(size_t)bx * 64 + c] = u2;
            }
        }
        float* mp = Mpart + (size_t)bx * 4096;
        #pragma unroll
        for (int r = 0; r < 16; ++r) {
            const int crow = (r & 3) + 8 * (r >> 2) + 4 * hi;
            mp[(qc * 32 + crow) * 64 + qk * 32 + l31] = acc[r];
        }
    }

    grid.sync();

    // ---------------- phase 2: fixed-order compact reduce (blocks 0..31) ----------------
    if (bx < BH) {
        const int bh = bx;
        const int e0 = tid * 16;
        f32x4 s[4] = {};
        #pragma unroll
        for (int p = 0; p < NPART; ++p) {
            const float* mq = Mpart + ((size_t)bh * NPART + p) * 4096 + e0;
            #pragma unroll
            for (int i = 0; i < 4; ++i) s[i] += *(const f32x4*)(mq + 4 * i);
        }
        ushort8v oh[2], ol[2];
        #pragma unroll
        for (int i = 0; i < 4; ++i)
            #pragma unroll
            for (int e = 0; e < 4; ++e) {
                unsigned short hh, ll;
                split_hl(s[i][e] * (1.0f / 2048.0f), hh, ll);
                oh[i >> 1][(i & 1) * 4 + e] = hh;
                ol[i >> 1][(i & 1) * 4 + e] = ll;
            }
        *(u32x4*)(MhiG + bh * 4096 + e0)     = __builtin_bit_cast(u32x4, oh[0]);
        *(u32x4*)(MhiG + bh * 4096 + e0 + 8) = __builtin_bit_cast(u32x4, oh[1]);
        *(u32x4*)(MloG + bh * 4096 + e0)     = __builtin_bit_cast(u32x4, ol[0]);
        *(u32x4*)(MloG + bh * 4096 + e0 + 8) = __builtin_bit_cast(u32x4, ol[1]);

        if (tid < 64) {
            float ks = 0.f;
            #pragma unroll
            for (int p = 0; p < NPART; ++p) ks += kpart[((size_t)bh * NPART + p) * 64 + tid];
            kssG[bh * 64 + tid] = ks * (1.0f / 2048.0f);
        } else if (tid < 128) {
            const int cc = tid - 64;
            float vs = 0.f;
            #pragma unroll
            for (int p = 0; p < NPART; ++p) vs += vpart[((size_t)bh * NPART + p) * 64 + cc];
            vsumG[bh * 64 + cc] = vs;
        }
    }

    grid.sync();

    // ---------------- phase 3: apply (512 blocks: qch = bx>>5, bh = bx&31) ----------------
    {
        unsigned char* Mh_b = smem;            // [64][64] bf16 swizzled
        unsigned char* Ml_b = smem + 8192;
        float* kssL = (float*)(smem + 16384);  // [64]
        float* vsL  = kssL + 64;               // [64]

        const int qch = bx >> 5, bh = bx & 31;
        const int b = bh >> 3, h = bh & 7;
        const int wave = tid >> 6, lane = tid & 63;
        const int l31 = lane & 31, hi = lane >> 5, r7 = l31 & 7;

        {
            const int c = tid >> 2, j = tid & 3;
            const int gb = bh * 4096 + c * 64 + j * 16;
            u32x4 a0 = *(const u32x4*)(MhiG + gb);
            u32x4 a1 = *(const u32x4*)(MhiG + gb + 8);
            u32x4 b0 = *(const u32x4*)(MloG + gb);
            u32x4 b1 = *(const u32x4*)(MloG + gb + 8);
            *(u32x4*)(Mh_b + c * 128 + 16 * ((2 * j) ^ (c & 7)))     = a0;
            *(u32x4*)(Mh_b + c * 128 + 16 * ((2 * j + 1) ^ (c & 7))) = a1;
            *(u32x4*)(Ml_b + c * 128 + 16 * ((2 * j) ^ (c & 7)))     = b0;
            *(u32x4*)(Ml_b + c * 128 + 16 * ((2 * j + 1) ^ (c & 7))) = b1;
            if (tid < 64) kssL[tid] = kssG[bh * 64 + tid];
            else if (tid < 128) vsL[tid - 64] = vsumG[bh * 64 + tid - 64];
        }

        const float* qg = qkv + ((size_t)b * 1536 + h * 64) * 2048;
        const int q = qch * 128 + wave * 32 + l31;
        float qf[4][8];
        #pragma unroll
        for (int ks = 0; ks < 4; ++ks)
            #pragma unroll
            for (int e = 0; e < 8; ++e)
                qf[ks][e] = qg[(size_t)(ks * 16 + hi * 8 + e) * 2048 + q];

        bf16x8 bH[4], bL[4];
        #pragma unroll
        for (int ks = 0; ks < 4; ++ks) {
            ushort8v uh, ul;
            #pragma unroll
            for (int e = 0; e < 8; ++e) {
                unsigned short hh, ll;
                split_hl(qf[ks][e], hh, ll);
                uh[e] = hh; ul[e] = ll;
            }
            bH[ks] = __builtin_bit_cast(bf16x8, uh);
            bL[ks] = __builtin_bit_cast(bf16x8, ul);
        }

        __syncthreads();

        bf16x8 aH[2][4], aL[2][4];
        #pragma unroll
        for (int ch = 0; ch < 2; ++ch) {
            const int row = (ch * 32 + l31) * 128;
            #pragma unroll
            for (int ks = 0; ks < 4; ++ks) {
                const int sl = 16 * ((2 * ks + hi) ^ r7);
                aH[ch][ks] = ldfrag(Mh_b + row + sl);
                aL[ch][ks] = ldfrag(Ml_b + row + sl);
            }
        }

        float dp = 0.f;
        #pragma unroll
        for (int ks = 0; ks < 4; ++ks) {
            const float* kp = kssL + 16 * ks + 8 * hi;
            #pragma unroll
            for (int e = 0; e < 8; ++e)
                dp = fmaf(qf[ks][e], kp[e], dp);
        }
        const float d  = 2048.0f + dp + __shfl_xor(dp, 32);
        const float rd = 1.0f / d;

        f32x16 acc0 = {}, acc1 = {};
        #pragma unroll
        for (int ks = 0; ks < 4; ++ks) {
            acc0 = mfma32(aH[0][ks], bH[ks], acc0);
            acc0 = mfma32(aH[0][ks], bL[ks], acc0);
            acc0 = mfma32(aL[0][ks], bH[ks], acc0);
            acc1 = mfma32(aH[1][ks], bH[ks], acc1);
            acc1 = mfma32(aH[1][ks], bL[ks], acc1);
            acc1 = mfma32(aL[1][ks], bH[ks], acc1);
        }

        float* ob = out + (size_t)bh * (64 * 2048) + qch * 128 + wave * 32 + l31;
        #pragma unroll
        for (int r = 0; r < 16; ++r) {
            const int crow = (r & 3) + 8 * (r >> 2) + 4 * hi;
            ob[(size_t)crow * 2048]        = (vsL[crow]      + acc0[r]) * rd;
            ob[(size_t)(32 + crow) * 2048] = (vsL[32 + crow] + acc1[r]) * rd;
        }
    }
}

extern "C" void kernel_launch(void* const* d_in, const int* in_sizes, int n_in,
                              void* d_out, int out_size, void* d_ws, size_t ws_size,
                              hipStream_t stream) {
    const float* qkv = (const float*)d_in[0];
    float* out = (float*)d_out;

    float* Mpart = (float*)d_ws;                               // 8 MB
    float* kpart = Mpart + (size_t)BH * NPART * 4096;          // 128 KB
    float* vpart = kpart + (size_t)BH * NPART * 64;            // 128 KB
    unsigned short* MhiG = (unsigned short*)(vpart + (size_t)BH * NPART * 64);  // 256 KB
    unsigned short* MloG = MhiG + (size_t)BH * 4096;           // 256 KB
    float* kssG  = (float*)(MloG + (size_t)BH * 4096);         // 8 KB
    float* vsumG = kssG + BH * 64;                             // 8 KB

    void* args[] = {(void*)&qkv, (void*)&Mpart, (void*)&kpart, (void*)&vpart,
                    (void*)&MhiG, (void*)&MloG, (void*)&kssG, (void*)&vsumG,
                    (void*)&out};
    hipLaunchCooperativeKernel((const void*)qattn_fused, dim3(BH * NPART), dim3(256),
                               args, 0, stream);
}

// Round 16
// 25.563 us; speedup vs baseline: 5.5344x; 5.5344x over previous
//
#include <hip/hip_runtime.h>
#include <hip/hip_bf16.h>

#define T_SEQ 2048
#define BH    32
#define NPART 16         // t-partials per head for M = V*K^T
#define PSTEP 2          // 64-wide steps per partial (NPART*PSTEP*64 == T_SEQ)

typedef __bf16 bf16x8 __attribute__((ext_vector_type(8)));
typedef float f32x4 __attribute__((ext_vector_type(4)));
typedef float f32x16 __attribute__((ext_vector_type(16)));
typedef unsigned int u32x4 __attribute__((ext_vector_type(4)));
typedef unsigned short ushort8v __attribute__((ext_vector_type(8)));

__device__ __forceinline__ unsigned short f2bf(float x) {
    __hip_bfloat16 b = __float2bfloat16(x);
    return __builtin_bit_cast(unsigned short, b);
}
__device__ __forceinline__ float bf2f(unsigned short u) {
    unsigned v = (unsigned)u << 16;
    return __builtin_bit_cast(float, v);
}
__device__ __forceinline__ void split_hl(float v, unsigned short& hi, unsigned short& lo) {
    hi = f2bf(v);
    lo = f2bf(v - bf2f(hi));
}
__device__ __forceinline__ unsigned pk2(unsigned short a, unsigned short b) {
    return (unsigned)a | ((unsigned)b << 16);
}
__device__ __forceinline__ f32x16 mfma32(bf16x8 a, bf16x8 b, f32x16 c) {
    return __builtin_amdgcn_mfma_f32_32x32x16_bf16(a, b, c, 0, 0, 0);
}
__device__ __forceinline__ bf16x8 ldfrag(const unsigned char* p) {
    return __builtin_bit_cast(bf16x8, *reinterpret_cast<const u32x4*>(p));
}

// ============ Kernel A: partial M = V*K^T over 128-wide t-slices ============
// 512 blocks, XCD-swizzled: xcd = id&7 serves heads 4*xcd..4*xcd+3
__global__ __launch_bounds__(256, 4)
void qattn_build(const float* __restrict__ qkv,
                 float* __restrict__ Mpart, float* __restrict__ kpart,
                 float* __restrict__ vpart) {
    __shared__ __align__(16) unsigned char smem[32768];
    const int tid = threadIdx.x;
    const int id  = blockIdx.x;
    const int k   = id >> 3;                       // 0..63
    const int bh  = 4 * (id & 7) + (k >> 4);       // head (4 per XCD)
    const int part = k & (NPART - 1);
    const int pidx = bh * NPART + part;            // partial index

    const int b = bh >> 3, h = bh & 7;
    const int tbase = part * (PSTEP * 64);
    const float* kg = qkv + ((size_t)b * 1536 + 512 + h * 64) * 2048;
    const float* vg = qkv + ((size_t)b * 1536 + 1024 + h * 64) * 2048;

    unsigned char* Vhi_b = smem;
    unsigned char* Vlo_b = smem + 8192;
    unsigned char* Khi_b = smem + 16384;
    unsigned char* Klo_b = smem + 24576;

    const int c = tid >> 2, j = tid & 3;
    const int lane = tid & 63, l31 = lane & 31, hi = lane >> 5;
    const int wave = tid >> 6, qc = wave >> 1, qk = wave & 1;
    const int r7 = l31 & 7;

    f32x4 kv[4], vv[4];
    #pragma unroll
    for (int i = 0; i < 4; ++i) {
        kv[i] = *(const f32x4*)(kg + (size_t)c * 2048 + tbase + j * 16 + i * 4);
        vv[i] = *(const f32x4*)(vg + (size_t)c * 2048 + tbase + j * 16 + i * 4);
    }

    float ksum = 0.f, vsum = 0.f;
    f32x16 acc = {};

    for (int st = 0; st < PSTEP; ++st) {
        __syncthreads();
        unsigned short kh[16], kl[16], vh[16], vl[16];
        #pragma unroll
        for (int i = 0; i < 4; ++i)
            #pragma unroll
            for (int e = 0; e < 4; ++e) {
                float kx = kv[i][e], vx = vv[i][e];
                ksum += kx; vsum += vx;
                split_hl(kx, kh[i * 4 + e], kl[i * 4 + e]);
                split_hl(vx, vh[i * 4 + e], vl[i * 4 + e]);
            }
        const int s0a = c * 128 + 16 * ((2 * j) ^ (c & 7));
        const int s0b = c * 128 + 16 * ((2 * j + 1) ^ (c & 7));
        u32x4 w;
        w[0]=pk2(kh[0],kh[1]); w[1]=pk2(kh[2],kh[3]); w[2]=pk2(kh[4],kh[5]); w[3]=pk2(kh[6],kh[7]);
        *(u32x4*)(Khi_b + s0a) = w;
        w[0]=pk2(kh[8],kh[9]); w[1]=pk2(kh[10],kh[11]); w[2]=pk2(kh[12],kh[13]); w[3]=pk2(kh[14],kh[15]);
        *(u32x4*)(Khi_b + s0b) = w;
        w[0]=pk2(kl[0],kl[1]); w[1]=pk2(kl[2],kl[3]); w[2]=pk2(kl[4],kl[5]); w[3]=pk2(kl[6],kl[7]);
        *(u32x4*)(Klo_b + s0a) = w;
        w[0]=pk2(kl[8],kl[9]); w[1]=pk2(kl[10],kl[11]); w[2]=pk2(kl[12],kl[13]); w[3]=pk2(kl[14],kl[15]);
        *(u32x4*)(Klo_b + s0b) = w;
        w[0]=pk2(vh[0],vh[1]); w[1]=pk2(vh[2],vh[3]); w[2]=pk2(vh[4],vh[5]); w[3]=pk2(vh[6],vh[7]);
        *(u32x4*)(Vhi_b + s0a) = w;
        w[0]=pk2(vh[8],vh[9]); w[1]=pk2(vh[10],vh[11]); w[2]=pk2(vh[12],vh[13]); w[3]=pk2(vh[14],vh[15]);
        *(u32x4*)(Vhi_b + s0b) = w;
        w[0]=pk2(vl[0],vl[1]); w[1]=pk2(vl[2],vl[3]); w[2]=pk2(vl[4],vl[5]); w[3]=pk2(vl[6],vl[7]);
        *(u32x4*)(Vlo_b + s0a) = w;
        w[0]=pk2(vl[8],vl[9]); w[1]=pk2(vl[10],vl[11]); w[2]=pk2(vl[12],vl[13]); w[3]=pk2(vl[14],vl[15]);
        *(u32x4*)(Vlo_b + s0b) = w;

        if (st + 1 < PSTEP) {
            const int s0n = tbase + (st + 1) * 64;
            #pragma unroll
            for (int i = 0; i < 4; ++i) {
                kv[i] = *(const f32x4*)(kg + (size_t)c * 2048 + s0n + j * 16 + i * 4);
                vv[i] = *(const f32x4*)(vg + (size_t)c * 2048 + s0n + j * 16 + i * 4);
            }
        }
        __syncthreads();

        const int rowA = (qc * 32 + l31) * 128;
        const int rowB = (qk * 32 + l31) * 128;
        #pragma unroll
        for (int ks = 0; ks < 4; ++ks) {
            const int sl = 16 * ((2 * ks + hi) ^ r7);
            bf16x8 aH = ldfrag(Vhi_b + rowA + sl);
            bf16x8 aL = ldfrag(Vlo_b + rowA + sl);
            bf16x8 bH = ldfrag(Khi_b + rowB + sl);
            bf16x8 bL = ldfrag(Klo_b + rowB + sl);
            acc = mfma32(aH, bH, acc);
            acc = mfma32(aH, bL, acc);
            acc = mfma32(aL, bH, acc);
        }
    }

    // partial ksum/vsum (per c)
    {
        float t1 = ksum + __shfl_xor(ksum, 1);
        float t2 = t1 + __shfl_xor(t1, 2);
        float u1 = vsum + __shfl_xor(vsum, 1);
        float u2 = u1 + __shfl_xor(u1, 2);
        if (j == 0) {
            kpart[(size_t)pidx * 64 + c] = t2;
            vpart[(size_t)pidx * 64 + c] = u2;
        }
    }
    // partial M store (f32)
    float* mp = Mpart + (size_t)pidx * 4096;
    #pragma unroll
    for (int r = 0; r < 16; ++r) {
        const int crow = (r & 3) + 8 * (r >> 2) + 4 * hi;
        mp[(qc * 32 + crow) * 64 + qk * 32 + l31] = acc[r];
    }
}

// ============ Kernel B: fused reduce + apply, 512 threads (8 waves x 32 q) ============
// 256 blocks, XCD-swizzled with the SAME head<->XCD mapping as build (L2 reuse).
__global__ __launch_bounds__(512, 1)
void qattn_apply(const float* __restrict__ qkv,
                 const float* __restrict__ Mpart, const float* __restrict__ kpart,
                 const float* __restrict__ vpart, float* __restrict__ out) {
    __shared__ __align__(16) unsigned char sm[16896];
    unsigned char* Mh_b = sm;            // [64][64] bf16 swizzled
    unsigned char* Ml_b = sm + 8192;
    float* kssL = (float*)(sm + 16384);  // [64]
    float* vsL  = kssL + 64;             // [64]

    const int tid = threadIdx.x;
    const int id  = blockIdx.x;
    const int k   = id >> 3;                      // 0..31
    const int bh  = 4 * (id & 7) + (k >> 3);      // same mapping as build
    const int qch = k & 7;                        // 256-q chunk
    const int b = bh >> 3, h = bh & 7;
    const int wave = tid >> 6, lane = tid & 63;
    const int l31 = lane & 31, hi = lane >> 5, r7 = l31 & 7;

    // ---- fused M reduce (fixed order p=0..15) + hi/lo split -> LDS ----
    {
        const int e0 = tid * 8;                   // 512 threads x 8 elems = 4096
        const int c = tid >> 3, j8 = tid & 7;
        f32x4 s0 = {}, s1 = {};
        #pragma unroll
        for (int p = 0; p < NPART; ++p) {
            const float* mq = Mpart + ((size_t)bh * NPART + p) * 4096 + e0;
            s0 += *(const f32x4*)(mq);
            s1 += *(const f32x4*)(mq + 4);
        }
        ushort8v oh, ol;
        #pragma unroll
        for (int e = 0; e < 4; ++e) {
            unsigned short hh, ll;
            split_hl(s0[e] * (1.0f / 2048.0f), hh, ll);
            oh[e] = hh; ol[e] = ll;
            split_hl(s1[e] * (1.0f / 2048.0f), hh, ll);
            oh[4 + e] = hh; ol[4 + e] = ll;
        }
        *(u32x4*)(Mh_b + c * 128 + 16 * (j8 ^ (c & 7))) = __builtin_bit_cast(u32x4, oh);
        *(u32x4*)(Ml_b + c * 128 + 16 * (j8 ^ (c & 7))) = __builtin_bit_cast(u32x4, ol);

        if (tid < 64) {
            float ks = 0.f;
            #pragma unroll
            for (int p = 0; p < NPART; ++p) ks += kpart[((size_t)bh * NPART + p) * 64 + tid];
            kssL[tid] = ks * (1.0f / 2048.0f);
        } else if (tid < 128) {
            const int cc = tid - 64;
            float vs = 0.f;
            #pragma unroll
            for (int p = 0; p < NPART; ++p) vs += vpart[((size_t)bh * NPART + p) * 64 + cc];
            vsL[cc] = vs;
        }
    }

    // ---- Q loads (f32 direct; lanes span q -> coalesced per element) ----
    const float* qg = qkv + ((size_t)b * 1536 + h * 64) * 2048;
    const int q = qch * 256 + wave * 32 + l31;
    float qf[4][8];
    #pragma unroll
    for (int ks = 0; ks < 4; ++ks)
        #pragma unroll
        for (int e = 0; e < 8; ++e)
            qf[ks][e] = qg[(size_t)(ks * 16 + hi * 8 + e) * 2048 + q];

    // hi/lo split into B-fragments
    bf16x8 bH[4], bL[4];
    #pragma unroll
    for (int ks = 0; ks < 4; ++ks) {
        ushort8v uh, ul;
        #pragma unroll
        for (int e = 0; e < 8; ++e) {
            unsigned short hh, ll;
            split_hl(qf[ks][e], hh, ll);
            uh[e] = hh; ul[e] = ll;
        }
        bH[ks] = __builtin_bit_cast(bf16x8, uh);
        bL[ks] = __builtin_bit_cast(bf16x8, ul);
    }

    __syncthreads();

    // ---- A-frags (M rows) from LDS ----
    bf16x8 aH[2][4], aL[2][4];
    #pragma unroll
    for (int ch = 0; ch < 2; ++ch) {
        const int row = (ch * 32 + l31) * 128;
        #pragma unroll
        for (int ks = 0; ks < 4; ++ks) {
            const int sl = 16 * ((2 * ks + hi) ^ r7);
            aH[ch][ks] = ldfrag(Mh_b + row + sl);
            aL[ch][ks] = ldfrag(Ml_b + row + sl);
        }
    }

    // ---- d[q] = 2048 + kss . Q (f32 Q) ----
    float dp = 0.f;
    #pragma unroll
    for (int ks = 0; ks < 4; ++ks) {
        const float* kp = kssL + 16 * ks + 8 * hi;
        #pragma unroll
        for (int e = 0; e < 8; ++e)
            dp = fmaf(qf[ks][e], kp[e], dp);
    }
    const float d  = 2048.0f + dp + __shfl_xor(dp, 32);
    const float rd = 1.0f / d;

    // ---- MFMA: Msc * Q (hh + hl + lh) ----
    f32x16 acc0 = {}, acc1 = {};
    #pragma unroll
    for (int ks = 0; ks < 4; ++ks) {
        acc0 = mfma32(aH[0][ks], bH[ks], acc0);
        acc0 = mfma32(aH[0][ks], bL[ks], acc0);
        acc0 = mfma32(aL[0][ks], bH[ks], acc0);
        acc1 = mfma32(aH[1][ks], bH[ks], acc1);
        acc1 = mfma32(aH[1][ks], bL[ks], acc1);
        acc1 = mfma32(aL[1][ks], bH[ks], acc1);
    }

    // ---- store O[c][q] coalesced across lanes ----
    float* ob = out + (size_t)bh * (64 * 2048) + q;
    #pragma unroll
    for (int r = 0; r < 16; ++r) {
        const int crow = (r & 3) + 8 * (r >> 2) + 4 * hi;
        ob[(size_t)crow * 2048]        = (vsL[crow]      + acc0[r]) * rd;
        ob[(size_t)(32 + crow) * 2048] = (vsL[32 + crow] + acc1[r]) * rd;
    }
}

extern "C" void kernel_launch(void* const* d_in, const int* in_sizes, int n_in,
                              void* d_out, int out_size, void* d_ws, size_t ws_size,
                              hipStream_t stream) {
    const float* qkv = (const float*)d_in[0];
    float* out = (float*)d_out;

    float* Mpart = (float*)d_ws;                               // 8 MB
    float* kpart = Mpart + (size_t)BH * NPART * 4096;          // 128 KB
    float* vpart = kpart + (size_t)BH * NPART * 64;            // 128 KB

    qattn_build<<<dim3(BH * NPART), 256, 0, stream>>>(qkv, Mpart, kpart, vpart);
    qattn_apply<<<dim3(256), 512, 0, stream>>>(qkv, Mpart, kpart, vpart, out);
}

// Round 17
// 23.311 us; speedup vs baseline: 6.0692x; 1.0966x over previous
//
#include <hip/hip_runtime.h>
#include <hip/hip_bf16.h>

#define T_SEQ 2048
#define BH    32
#define NPART 16         // t-partials per head for M = V*K^T
#define PSTEP 2          // 64-wide steps per partial (NPART*PSTEP*64 == T_SEQ)

typedef __bf16 bf16x8 __attribute__((ext_vector_type(8)));
typedef float f32x4 __attribute__((ext_vector_type(4)));
typedef float f32x16 __attribute__((ext_vector_type(16)));
typedef unsigned int u32x4 __attribute__((ext_vector_type(4)));
typedef unsigned short ushort8v __attribute__((ext_vector_type(8)));

__device__ __forceinline__ unsigned short f2bf(float x) {
    __hip_bfloat16 b = __float2bfloat16(x);
    return __builtin_bit_cast(unsigned short, b);
}
__device__ __forceinline__ float bf2f(unsigned short u) {
    unsigned v = (unsigned)u << 16;
    return __builtin_bit_cast(float, v);
}
__device__ __forceinline__ void split_hl(float v, unsigned short& hi, unsigned short& lo) {
    hi = f2bf(v);
    lo = f2bf(v - bf2f(hi));
}
__device__ __forceinline__ unsigned pk2(unsigned short a, unsigned short b) {
    return (unsigned)a | ((unsigned)b << 16);
}
__device__ __forceinline__ f32x16 mfma32(bf16x8 a, bf16x8 b, f32x16 c) {
    return __builtin_amdgcn_mfma_f32_32x32x16_bf16(a, b, c, 0, 0, 0);
}
__device__ __forceinline__ bf16x8 ldfrag(const unsigned char* p) {
    return __builtin_bit_cast(bf16x8, *reinterpret_cast<const u32x4*>(p));
}

// ============ Kernel A: partial M = Vhi*(Khi+Klo)^T over 128-wide t-slices ============
// 512 blocks, XCD-swizzled: xcd = id&7 serves heads 4*xcd..4*xcd+3
__global__ __launch_bounds__(256, 4)
void qattn_build(const float* __restrict__ qkv,
                 float* __restrict__ Mpart, float* __restrict__ kpart,
                 float* __restrict__ vpart) {
    __shared__ __align__(16) unsigned char smem[24576];
    const int tid = threadIdx.x;
    const int id  = blockIdx.x;
    const int k   = id >> 3;                       // 0..63
    const int bh  = 4 * (id & 7) + (k >> 4);       // head (4 per XCD)
    const int part = k & (NPART - 1);
    const int pidx = bh * NPART + part;            // partial index

    const int b = bh >> 3, h = bh & 7;
    const int tbase = part * (PSTEP * 64);
    const float* kg = qkv + ((size_t)b * 1536 + 512 + h * 64) * 2048;
    const float* vg = qkv + ((size_t)b * 1536 + 1024 + h * 64) * 2048;

    unsigned char* Vhi_b = smem;
    unsigned char* Khi_b = smem + 8192;
    unsigned char* Klo_b = smem + 16384;

    const int c = tid >> 2, j = tid & 3;
    const int lane = tid & 63, l31 = lane & 31, hi = lane >> 5;
    const int wave = tid >> 6, qc = wave >> 1, qk = wave & 1;
    const int r7 = l31 & 7;

    f32x4 kv[4], vv[4];
    #pragma unroll
    for (int i = 0; i < 4; ++i) {
        kv[i] = *(const f32x4*)(kg + (size_t)c * 2048 + tbase + j * 16 + i * 4);
        vv[i] = *(const f32x4*)(vg + (size_t)c * 2048 + tbase + j * 16 + i * 4);
    }

    float ksum = 0.f, vsum = 0.f;
    f32x16 acc = {};

    for (int st = 0; st < PSTEP; ++st) {
        __syncthreads();
        unsigned short kh[16], kl[16], vh[16];
        #pragma unroll
        for (int i = 0; i < 4; ++i)
            #pragma unroll
            for (int e = 0; e < 4; ++e) {
                float kx = kv[i][e], vx = vv[i][e];
                ksum += kx; vsum += vx;
                split_hl(kx, kh[i * 4 + e], kl[i * 4 + e]);
                vh[i * 4 + e] = f2bf(vx);
            }
        const int s0a = c * 128 + 16 * ((2 * j) ^ (c & 7));
        const int s0b = c * 128 + 16 * ((2 * j + 1) ^ (c & 7));
        u32x4 w;
        w[0]=pk2(kh[0],kh[1]); w[1]=pk2(kh[2],kh[3]); w[2]=pk2(kh[4],kh[5]); w[3]=pk2(kh[6],kh[7]);
        *(u32x4*)(Khi_b + s0a) = w;
        w[0]=pk2(kh[8],kh[9]); w[1]=pk2(kh[10],kh[11]); w[2]=pk2(kh[12],kh[13]); w[3]=pk2(kh[14],kh[15]);
        *(u32x4*)(Khi_b + s0b) = w;
        w[0]=pk2(kl[0],kl[1]); w[1]=pk2(kl[2],kl[3]); w[2]=pk2(kl[4],kl[5]); w[3]=pk2(kl[6],kl[7]);
        *(u32x4*)(Klo_b + s0a) = w;
        w[0]=pk2(kl[8],kl[9]); w[1]=pk2(kl[10],kl[11]); w[2]=pk2(kl[12],kl[13]); w[3]=pk2(kl[14],kl[15]);
        *(u32x4*)(Klo_b + s0b) = w;
        w[0]=pk2(vh[0],vh[1]); w[1]=pk2(vh[2],vh[3]); w[2]=pk2(vh[4],vh[5]); w[3]=pk2(vh[6],vh[7]);
        *(u32x4*)(Vhi_b + s0a) = w;
        w[0]=pk2(vh[8],vh[9]); w[1]=pk2(vh[10],vh[11]); w[2]=pk2(vh[12],vh[13]); w[3]=pk2(vh[14],vh[15]);
        *(u32x4*)(Vhi_b + s0b) = w;

        if (st + 1 < PSTEP) {
            const int s0n = tbase + (st + 1) * 64;
            #pragma unroll
            for (int i = 0; i < 4; ++i) {
                kv[i] = *(const f32x4*)(kg + (size_t)c * 2048 + s0n + j * 16 + i * 4);
                vv[i] = *(const f32x4*)(vg + (size_t)c * 2048 + s0n + j * 16 + i * 4);
            }
        }
        __syncthreads();

        const int rowA = (qc * 32 + l31) * 128;
        const int rowB = (qk * 32 + l31) * 128;
        #pragma unroll
        for (int ks = 0; ks < 4; ++ks) {
            const int sl = 16 * ((2 * ks + hi) ^ r7);
            bf16x8 aH = ldfrag(Vhi_b + rowA + sl);
            bf16x8 bH = ldfrag(Khi_b + rowB + sl);
            bf16x8 bL = ldfrag(Klo_b + rowB + sl);
            acc = mfma32(aH, bH, acc);
            acc = mfma32(aH, bL, acc);
        }
    }

    // partial ksum/vsum (per c)
    {
        float t1 = ksum + __shfl_xor(ksum, 1);
        float t2 = t1 + __shfl_xor(t1, 2);
        float u1 = vsum + __shfl_xor(vsum, 1);
        float u2 = u1 + __shfl_xor(u1, 2);
        if (j == 0) {
            kpart[(size_t)pidx * 64 + c] = t2;
            vpart[(size_t)pidx * 64 + c] = u2;
        }
    }
    // partial M store (f32)
    float* mp = Mpart + (size_t)pidx * 4096;
    #pragma unroll
    for (int r = 0; r < 16; ++r) {
        const int crow = (r & 3) + 8 * (r >> 2) + 4 * hi;
        mp[(qc * 32 + crow) * 64 + qk * 32 + l31] = acc[r];
    }
}

// ============ Kernel B: fused reduce + apply, 512 threads (8 waves x 32 q) ============
// 256 blocks, XCD-swizzled with the SAME head<->XCD mapping as build (L2 reuse).
__global__ __launch_bounds__(512, 1)
void qattn_apply(const float* __restrict__ qkv,
                 const float* __restrict__ Mpart, const float* __restrict__ kpart,
                 const float* __restrict__ vpart, float* __restrict__ out) {
    __shared__ __align__(16) unsigned char sm[16896];
    unsigned char* Mh_b = sm;            // [64][64] bf16 swizzled
    unsigned char* Ml_b = sm + 8192;
    float* kssL = (float*)(sm + 16384);  // [64]
    float* vsL  = kssL + 64;             // [64]

    const int tid = threadIdx.x;
    const int id  = blockIdx.x;
    const int k   = id >> 3;                      // 0..31
    const int bh  = 4 * (id & 7) + (k >> 3);      // same mapping as build
    const int qch = k & 7;                        // 256-q chunk
    const int b = bh >> 3, h = bh & 7;
    const int wave = tid >> 6, lane = tid & 63;
    const int l31 = lane & 31, hi = lane >> 5, r7 = l31 & 7;

    // ---- fused M reduce (fixed order p=0..15) + hi/lo split -> LDS ----
    {
        const int e0 = tid * 8;                   // 512 threads x 8 elems = 4096
        const int c = tid >> 3, j8 = tid & 7;
        f32x4 s0 = {}, s1 = {};
        #pragma unroll
        for (int p = 0; p < NPART; ++p) {
            const float* mq = Mpart + ((size_t)bh * NPART + p) * 4096 + e0;
            s0 += *(const f32x4*)(mq);
            s1 += *(const f32x4*)(mq + 4);
        }
        ushort8v oh, ol;
        #pragma unroll
        for (int e = 0; e < 4; ++e) {
            unsigned short hh, ll;
            split_hl(s0[e] * (1.0f / 2048.0f), hh, ll);
            oh[e] = hh; ol[e] = ll;
            split_hl(s1[e] * (1.0f / 2048.0f), hh, ll);
            oh[4 + e] = hh; ol[4 + e] = ll;
        }
        *(u32x4*)(Mh_b + c * 128 + 16 * (j8 ^ (c & 7))) = __builtin_bit_cast(u32x4, oh);
        *(u32x4*)(Ml_b + c * 128 + 16 * (j8 ^ (c & 7))) = __builtin_bit_cast(u32x4, ol);

        if (tid < 64) {
            float ks = 0.f;
            #pragma unroll
            for (int p = 0; p < NPART; ++p) ks += kpart[((size_t)bh * NPART + p) * 64 + tid];
            kssL[tid] = ks * (1.0f / 2048.0f);
        } else if (tid < 128) {
            const int cc = tid - 64;
            float vs = 0.f;
            #pragma unroll
            for (int p = 0; p < NPART; ++p) vs += vpart[((size_t)bh * NPART + p) * 64 + cc];
            vsL[cc] = vs;
        }
    }

    // ---- Q loads (f32 direct; lanes span q -> coalesced per element) ----
    const float* qg = qkv + ((size_t)b * 1536 + h * 64) * 2048;
    const int q = qch * 256 + wave * 32 + l31;
    float qf[4][8];
    #pragma unroll
    for (int ks = 0; ks < 4; ++ks)
        #pragma unroll
        for (int e = 0; e < 8; ++e)
            qf[ks][e] = qg[(size_t)(ks * 16 + hi * 8 + e) * 2048 + q];

    // hi/lo split into B-fragments
    bf16x8 bH[4], bL[4];
    #pragma unroll
    for (int ks = 0; ks < 4; ++ks) {
        ushort8v uh, ul;
        #pragma unroll
        for (int e = 0; e < 8; ++e) {
            unsigned short hh, ll;
            split_hl(qf[ks][e], hh, ll);
            uh[e] = hh; ul[e] = ll;
        }
        bH[ks] = __builtin_bit_cast(bf16x8, uh);
        bL[ks] = __builtin_bit_cast(bf16x8, ul);
    }

    __syncthreads();

    // ---- A-frags (M rows) from LDS ----
    bf16x8 aH[2][4], aL[2][4];
    #pragma unroll
    for (int ch = 0; ch < 2; ++ch) {
        const int row = (ch * 32 + l31) * 128;
        #pragma unroll
        for (int ks = 0; ks < 4; ++ks) {
            const int sl = 16 * ((2 * ks + hi) ^ r7);
            aH[ch][ks] = ldfrag(Mh_b + row + sl);
            aL[ch][ks] = ldfrag(Ml_b + row + sl);
        }
    }

    // ---- d[q] = 2048 + kss . Q (f32 Q) ----
    float dp = 0.f;
    #pragma unroll
    for (int ks = 0; ks < 4; ++ks) {
        const float* kp = kssL + 16 * ks + 8 * hi;
        #pragma unroll
        for (int e = 0; e < 8; ++e)
            dp = fmaf(qf[ks][e], kp[e], dp);
    }
    const float d  = 2048.0f + dp + __shfl_xor(dp, 32);
    const float rd = 1.0f / d;

    // ---- MFMA: Msc * Q (hh + hl + lh) ----
    f32x16 acc0 = {}, acc1 = {};
    #pragma unroll
    for (int ks = 0; ks < 4; ++ks) {
        acc0 = mfma32(aH[0][ks], bH[ks], acc0);
        acc0 = mfma32(aH[0][ks], bL[ks], acc0);
        acc0 = mfma32(aL[0][ks], bH[ks], acc0);
        acc1 = mfma32(aH[1][ks], bH[ks], acc1);
        acc1 = mfma32(aH[1][ks], bL[ks], acc1);
        acc1 = mfma32(aL[1][ks], bH[ks], acc1);
    }

    // ---- store O[c][q] coalesced across lanes ----
    float* ob = out + (size_t)bh * (64 * 2048) + q;
    #pragma unroll
    for (int r = 0; r < 16; ++r) {
        const int crow = (r & 3) + 8 * (r >> 2) + 4 * hi;
        ob[(size_t)crow * 2048]        = (vsL[crow]      + acc0[r]) * rd;
        ob[(size_t)(32 + crow) * 2048] = (vsL[32 + crow] + acc1[r]) * rd;
    }
}

extern "C" void kernel_launch(void* const* d_in, const int* in_sizes, int n_in,
                              void* d_out, int out_size, void* d_ws, size_t ws_size,
                              hipStream_t stream) {
    const float* qkv = (const float*)d_in[0];
    float* out = (float*)d_out;

    float* Mpart = (float*)d_ws;                               // 8 MB
    float* kpart = Mpart + (size_t)BH * NPART * 4096;          // 128 KB
    float* vpart = kpart + (size_t)BH * NPART * 64;            // 128 KB

    qattn_build<<<dim3(BH * NPART), 256, 0, stream>>>(qkv, Mpart, kpart, vpart);
    qattn_apply<<<dim3(256), 512, 0, stream>>>(qkv, Mpart, kpart, vpart, out);
}

// Round 18
// 20.498 us; speedup vs baseline: 6.9019x; 1.1372x over previous
//
#include <hip/hip_runtime.h>
#include <hip/hip_bf16.h>

#define T_SEQ 2048
#define BH    32
#define NPART 16         // t-partials per head for M = V*K^T
#define PSTEP 2          // 64-wide steps per partial (NPART*PSTEP*64 == T_SEQ)

typedef __bf16 bf16x8 __attribute__((ext_vector_type(8)));
typedef float f32x4 __attribute__((ext_vector_type(4)));
typedef float f32x16 __attribute__((ext_vector_type(16)));
typedef unsigned int u32x4 __attribute__((ext_vector_type(4)));
typedef unsigned short ushort8v __attribute__((ext_vector_type(8)));

__device__ __forceinline__ unsigned short f2bf(float x) {
    __hip_bfloat16 b = __float2bfloat16(x);
    return __builtin_bit_cast(unsigned short, b);
}
__device__ __forceinline__ float bf2f(unsigned short u) {
    unsigned v = (unsigned)u << 16;
    return __builtin_bit_cast(float, v);
}
__device__ __forceinline__ unsigned pk2(unsigned short a, unsigned short b) {
    return (unsigned)a | ((unsigned)b << 16);
}
__device__ __forceinline__ f32x16 mfma32(bf16x8 a, bf16x8 b, f32x16 c) {
    return __builtin_amdgcn_mfma_f32_32x32x16_bf16(a, b, c, 0, 0, 0);
}
__device__ __forceinline__ bf16x8 ldfrag(const unsigned char* p) {
    return __builtin_bit_cast(bf16x8, *reinterpret_cast<const u32x4*>(p));
}

// ============ Kernel A: partial M = bf16(V)*bf16(K)^T over 128-wide t-slices ============
// 512 blocks, XCD-swizzled: xcd = id&7 serves heads 4*xcd..4*xcd+3
__global__ __launch_bounds__(256, 4)
void qattn_build(const float* __restrict__ qkv,
                 unsigned short* __restrict__ Mpart16, float* __restrict__ kpart,
                 float* __restrict__ vpart) {
    __shared__ __align__(16) unsigned char smem[16384];
    const int tid = threadIdx.x;
    const int id  = blockIdx.x;
    const int k   = id >> 3;                       // 0..63
    const int bh  = 4 * (id & 7) + (k >> 4);       // head (4 per XCD)
    const int part = k & (NPART - 1);
    const int pidx = bh * NPART + part;            // partial index

    const int b = bh >> 3, h = bh & 7;
    const int tbase = part * (PSTEP * 64);
    const float* kg = qkv + ((size_t)b * 1536 + 512 + h * 64) * 2048;
    const float* vg = qkv + ((size_t)b * 1536 + 1024 + h * 64) * 2048;

    unsigned char* Vb = smem;
    unsigned char* Kb = smem + 8192;

    const int c = tid >> 2, j = tid & 3;
    const int lane = tid & 63, l31 = lane & 31, hi = lane >> 5;
    const int wave = tid >> 6, qc = wave >> 1, qk = wave & 1;
    const int r7 = l31 & 7;

    f32x4 kv[4], vv[4];
    #pragma unroll
    for (int i = 0; i < 4; ++i) {
        kv[i] = *(const f32x4*)(kg + (size_t)c * 2048 + tbase + j * 16 + i * 4);
        vv[i] = *(const f32x4*)(vg + (size_t)c * 2048 + tbase + j * 16 + i * 4);
    }

    float ksum = 0.f, vsum = 0.f;
    f32x16 acc = {};

    for (int st = 0; st < PSTEP; ++st) {
        __syncthreads();
        unsigned short kh[16], vh[16];
        #pragma unroll
        for (int i = 0; i < 4; ++i)
            #pragma unroll
            for (int e = 0; e < 4; ++e) {
                float kx = kv[i][e], vx = vv[i][e];
                ksum += kx; vsum += vx;
                kh[i * 4 + e] = f2bf(kx);
                vh[i * 4 + e] = f2bf(vx);
            }
        const int s0a = c * 128 + 16 * ((2 * j) ^ (c & 7));
        const int s0b = c * 128 + 16 * ((2 * j + 1) ^ (c & 7));
        u32x4 w;
        w[0]=pk2(kh[0],kh[1]); w[1]=pk2(kh[2],kh[3]); w[2]=pk2(kh[4],kh[5]); w[3]=pk2(kh[6],kh[7]);
        *(u32x4*)(Kb + s0a) = w;
        w[0]=pk2(kh[8],kh[9]); w[1]=pk2(kh[10],kh[11]); w[2]=pk2(kh[12],kh[13]); w[3]=pk2(kh[14],kh[15]);
        *(u32x4*)(Kb + s0b) = w;
        w[0]=pk2(vh[0],vh[1]); w[1]=pk2(vh[2],vh[3]); w[2]=pk2(vh[4],vh[5]); w[3]=pk2(vh[6],vh[7]);
        *(u32x4*)(Vb + s0a) = w;
        w[0]=pk2(vh[8],vh[9]); w[1]=pk2(vh[10],vh[11]); w[2]=pk2(vh[12],vh[13]); w[3]=pk2(vh[14],vh[15]);
        *(u32x4*)(Vb + s0b) = w;

        if (st + 1 < PSTEP) {
            const int s0n = tbase + (st + 1) * 64;
            #pragma unroll
            for (int i = 0; i < 4; ++i) {
                kv[i] = *(const f32x4*)(kg + (size_t)c * 2048 + s0n + j * 16 + i * 4);
                vv[i] = *(const f32x4*)(vg + (size_t)c * 2048 + s0n + j * 16 + i * 4);
            }
        }
        __syncthreads();

        const int rowA = (qc * 32 + l31) * 128;
        const int rowB = (qk * 32 + l31) * 128;
        #pragma unroll
        for (int ks = 0; ks < 4; ++ks) {
            const int sl = 16 * ((2 * ks + hi) ^ r7);
            acc = mfma32(ldfrag(Vb + rowA + sl), ldfrag(Kb + rowB + sl), acc);
        }
    }

    // partial ksum/vsum (per c)
    {
        float t1 = ksum + __shfl_xor(ksum, 1);
        float t2 = t1 + __shfl_xor(t1, 2);
        float u1 = vsum + __shfl_xor(vsum, 1);
        float u2 = u1 + __shfl_xor(u1, 2);
        if (j == 0) {
            kpart[(size_t)pidx * 64 + c] = t2;
            vpart[(size_t)pidx * 64 + c] = u2;
        }
    }
    // partial M store (bf16, 1/2048 folded)
    unsigned short* mp = Mpart16 + (size_t)pidx * 4096;
    #pragma unroll
    for (int r = 0; r < 16; ++r) {
        const int crow = (r & 3) + 8 * (r >> 2) + 4 * hi;
        mp[(qc * 32 + crow) * 64 + qk * 32 + l31] = f2bf(acc[r] * (1.0f / 2048.0f));
    }
}

// ============ Kernel B: fused reduce + apply, 512 threads (8 waves x 32 q) ============
// 256 blocks, XCD-swizzled with the SAME head<->XCD mapping as build (L2 reuse).
__global__ __launch_bounds__(512, 1)
void qattn_apply(const float* __restrict__ qkv,
                 const unsigned short* __restrict__ Mpart16, const float* __restrict__ kpart,
                 const float* __restrict__ vpart, float* __restrict__ out) {
    __shared__ __align__(16) unsigned char sm[8704];
    unsigned char* Mh_b = sm;            // [64][64] bf16 swizzled
    float* kssL = (float*)(sm + 8192);   // [64]
    float* vsL  = kssL + 64;             // [64]

    const int tid = threadIdx.x;
    const int id  = blockIdx.x;
    const int k   = id >> 3;                      // 0..31
    const int bh  = 4 * (id & 7) + (k >> 3);      // same mapping as build
    const int qch = k & 7;                        // 256-q chunk
    const int b = bh >> 3, h = bh & 7;
    const int wave = tid >> 6, lane = tid & 63;
    const int l31 = lane & 31, hi = lane >> 5, r7 = l31 & 7;

    // ---- fused M reduce (fixed order p=0..15, bf16 partials) -> bf16 LDS ----
    {
        const int e0 = tid * 8;                   // 512 threads x 8 elems = 4096
        const int c = tid >> 3, j8 = tid & 7;
        float s[8] = {};
        #pragma unroll
        for (int p = 0; p < NPART; ++p) {
            ushort8v mv = *(const ushort8v*)(Mpart16 + ((size_t)bh * NPART + p) * 4096 + e0);
            #pragma unroll
            for (int e = 0; e < 8; ++e) s[e] += bf2f(mv[e]);
        }
        ushort8v oh;
        #pragma unroll
        for (int e = 0; e < 8; ++e) oh[e] = f2bf(s[e]);
        *(u32x4*)(Mh_b + c * 128 + 16 * (j8 ^ (c & 7))) = __builtin_bit_cast(u32x4, oh);

        if (tid < 64) {
            float ks = 0.f;
            #pragma unroll
            for (int p = 0; p < NPART; ++p) ks += kpart[((size_t)bh * NPART + p) * 64 + tid];
            kssL[tid] = ks * (1.0f / 2048.0f);
        } else if (tid < 128) {
            const int cc = tid - 64;
            float vs = 0.f;
            #pragma unroll
            for (int p = 0; p < NPART; ++p) vs += vpart[((size_t)bh * NPART + p) * 64 + cc];
            vsL[cc] = vs;
        }
    }

    // ---- Q loads (f32 direct; lanes span q -> coalesced per element) ----
    const float* qg = qkv + ((size_t)b * 1536 + h * 64) * 2048;
    const int q = qch * 256 + wave * 32 + l31;
    float qf[4][8];
    #pragma unroll
    for (int ks = 0; ks < 4; ++ks)
        #pragma unroll
        for (int e = 0; e < 8; ++e)
            qf[ks][e] = qg[(size_t)(ks * 16 + hi * 8 + e) * 2048 + q];

    // single-bf16 B-fragments
    bf16x8 bF[4];
    #pragma unroll
    for (int ks = 0; ks < 4; ++ks) {
        ushort8v uh;
        #pragma unroll
        for (int e = 0; e < 8; ++e) uh[e] = f2bf(qf[ks][e]);
        bF[ks] = __builtin_bit_cast(bf16x8, uh);
    }

    __syncthreads();

    // ---- A-frags (Msc rows) from LDS ----
    bf16x8 aF[2][4];
    #pragma unroll
    for (int ch = 0; ch < 2; ++ch) {
        const int row = (ch * 32 + l31) * 128;
        #pragma unroll
        for (int ks = 0; ks < 4; ++ks) {
            const int sl = 16 * ((2 * ks + hi) ^ r7);
            aF[ch][ks] = ldfrag(Mh_b + row + sl);
        }
    }

    // ---- d[q] = 2048 + kss . Q (f32 Q) ----
    float dp = 0.f;
    #pragma unroll
    for (int ks = 0; ks < 4; ++ks) {
        const float* kp = kssL + 16 * ks + 8 * hi;
        #pragma unroll
        for (int e = 0; e < 8; ++e)
            dp = fmaf(qf[ks][e], kp[e], dp);
    }
    const float d  = 2048.0f + dp + __shfl_xor(dp, 32);
    const float rd = 1.0f / d;

    // ---- MFMA: Msc * Q (single bf16) ----
    f32x16 acc0 = {}, acc1 = {};
    #pragma unroll
    for (int ks = 0; ks < 4; ++ks) {
        acc0 = mfma32(aF[0][ks], bF[ks], acc0);
        acc1 = mfma32(aF[1][ks], bF[ks], acc1);
    }

    // ---- store O[c][q] coalesced across lanes ----
    float* ob = out + (size_t)bh * (64 * 2048) + q;
    #pragma unroll
    for (int r = 0; r < 16; ++r) {
        const int crow = (r & 3) + 8 * (r >> 2) + 4 * hi;
        ob[(size_t)crow * 2048]        = (vsL[crow]      + acc0[r]) * rd;
        ob[(size_t)(32 + crow) * 2048] = (vsL[32 + crow] + acc1[r]) * rd;
    }
}

extern "C" void kernel_launch(void* const* d_in, const int* in_sizes, int n_in,
                              void* d_out, int out_size, void* d_ws, size_t ws_size,
                              hipStream_t stream) {
    const float* qkv = (const float*)d_in[0];
    float* out = (float*)d_out;

    unsigned short* Mpart16 = (unsigned short*)d_ws;                 // 4 MB bf16
    float* kpart = (float*)(Mpart16 + (size_t)BH * NPART * 4096);    // 128 KB
    float* vpart = kpart + (size_t)BH * NPART * 64;                  // 128 KB

    qattn_build<<<dim3(BH * NPART), 256, 0, stream>>>(qkv, Mpart16, kpart, vpart);
    qattn_apply<<<dim3(256), 512, 0, stream>>>(qkv, Mpart16, kpart, vpart, out);
}